// Round 1
// baseline (2320.323 us; speedup 1.0000x reference)
//
#include <hip/hip_runtime.h>

// EquivSetGNN forward, MI355X. All f32. Key ideas:
//  - seg_mean(cat([x[src],Xe[dst]])@W2) folded to cat(x, seg_mean(Xe[dst]))@W2 (linearity).
//  - v2e_src / all_batch sorted -> pull-based E->V and readout via binary search (no atomics).
//  - Matmuls (K=64/128, J=64): wave-per-row, W column in VGPRs, A row distributed over
//    lanes, inner loop = v_readlane + fma (no LDS traffic).

constexpr int N_NODES = 100000;
constexpr int N_EDGES = 50000;
constexpr int NNZ_C   = 1280000;
constexpr int NGRAPH  = 256;

__device__ __forceinline__ float rl(float v, int k) {
  return __int_as_float(__builtin_amdgcn_readlane(__float_as_int(v), k));
}

__device__ __forceinline__ int lower_bound_i(const int* a, int n, int v) {
  int lo = 0, hi = n;
  while (lo < hi) { int m = (lo + hi) >> 1; if (a[m] < v) lo = m + 1; else hi = m; }
  return lo;
}

// ---- edge counts (dst is unsorted) ----
__global__ void count_edges_k(const int* __restrict__ dst, float* __restrict__ cntE, int nnz) {
  int i = blockIdx.x * blockDim.x + threadIdx.x;
  if (i < nnz) atomicAdd(&cntE[dst[i]], 1.0f);
}

__global__ void inv_k(const float* __restrict__ cntE, float* __restrict__ invE, int e) {
  int i = blockIdx.x * blockDim.x + threadIdx.x;
  if (i < e) invE[i] = 1.0f / fmaxf(cntE[i], 1.0f);
}

// ---- x = relu(X @ W_in + b_in); also copy to x0.  K=128, J=64 ----
__global__ void __launch_bounds__(256) mm_in_k(const float* __restrict__ A,
    const float* __restrict__ W, const float* __restrict__ b,
    float* __restrict__ C, float* __restrict__ C2, int n) {
  int lane = threadIdx.x & 63;
  int wid  = (blockIdx.x * blockDim.x + threadIdx.x) >> 6;
  int nw   = (gridDim.x * blockDim.x) >> 6;
  float w[128];
#pragma unroll
  for (int k = 0; k < 128; ++k) w[k] = W[k * 64 + lane];
  float bb = b[lane];
  for (int row = wid; row < n; row += nw) {
    float alo = A[(size_t)row * 128 + lane];
    float ahi = A[(size_t)row * 128 + 64 + lane];
    float acc = bb;
#pragma unroll
    for (int k = 0; k < 64; ++k) acc = fmaf(rl(alo, k), w[k], acc);
#pragma unroll
    for (int k = 0; k < 64; ++k) acc = fmaf(rl(ahi, k), w[64 + k], acc);
    acc = fmaxf(acc, 0.0f);
    C[(size_t)row * 64 + lane]  = acc;
    C2[(size_t)row * 64 + lane] = acc;
  }
}

// ---- C = [relu](A @ W + b); K=64, J=64; safe in-place (row-local) ----
// NOTE: no __restrict__ on A/C: called with A==C (in-place).
template <bool RELU>
__global__ void __launch_bounds__(256) mm64_k(const float* A,
    const float* __restrict__ W, const float* __restrict__ b, float* C, int n) {
  int lane = threadIdx.x & 63;
  int wid  = (blockIdx.x * blockDim.x + threadIdx.x) >> 6;
  int nw   = (gridDim.x * blockDim.x) >> 6;
  float w[64];
#pragma unroll
  for (int k = 0; k < 64; ++k) w[k] = W[k * 64 + lane];
  float bb = b[lane];
  for (int row = wid; row < n; row += nw) {
    float a = A[(size_t)row * 64 + lane];
    float acc = bb;
#pragma unroll
    for (int k = 0; k < 64; ++k) acc = fmaf(rl(a, k), w[k], acc);
    if (RELU) acc = fmaxf(acc, 0.0f);
    C[(size_t)row * 64 + lane] = acc;
  }
}

// ---- V->E scatter-sum: Xe[dst[i]] += h[src[i]]  (atomics; dst unsorted) ----
__global__ void scatter_ve_k(const float* __restrict__ h, const int* __restrict__ src,
    const int* __restrict__ dst, float* __restrict__ Xe, int nnz) {
  int i = blockIdx.x * blockDim.x + threadIdx.x;
  int nz = i >> 6, j = i & 63;
  if (nz < nnz) {
    int s = src[nz], e = dst[nz];
    atomicAdd(&Xe[(size_t)e * 64 + j], h[(size_t)s * 64 + j]);
  }
}

// ---- fused: z = seg_mean(Xe_mean[dst], src);  xv = cat(x, z) @ W2 + b2 (masked);
//      x = 0.5*xv + 0.5*x0.  src is sorted -> binary-search segment, no atomics. ----
__global__ void __launch_bounds__(256) e2v_catmm_k(const float* __restrict__ Xe,
    const float* __restrict__ invE, const int* __restrict__ src, const int* __restrict__ dst,
    float* x /* in-out */, const float* __restrict__ x0,
    const float* __restrict__ W2, const float* __restrict__ b2, int nnz, int n) {
  int lane = threadIdx.x & 63;
  int wid  = (blockIdx.x * blockDim.x + threadIdx.x) >> 6;
  int nw   = (gridDim.x * blockDim.x) >> 6;
  float w[128];
#pragma unroll
  for (int k = 0; k < 128; ++k) w[k] = W2[k * 64 + lane];
  float bb = b2[lane];
  for (int node = wid; node < n; node += nw) {
    int lo = lower_bound_i(src, nnz, node);
    int hi = lower_bound_i(src, nnz, node + 1);
    float z = 0.0f;
    for (int i = lo; i < hi; ++i) {
      int e = dst[i];                       // wave-uniform load
      z = fmaf(Xe[(size_t)e * 64 + lane], invE[e], z);
    }
    float res = 0.5f * x0[(size_t)node * 64 + lane];
    if (hi > lo) {                          // wave-uniform branch
      float zm = z / (float)(hi - lo);
      float a1 = x[(size_t)node * 64 + lane];
      float acc = bb;
#pragma unroll
      for (int k = 0; k < 64; ++k) acc = fmaf(rl(a1, k), w[k], acc);
#pragma unroll
      for (int k = 0; k < 64; ++k) acc = fmaf(rl(zm, k), w[64 + k], acc);
      res = fmaf(0.5f, acc, res);
    }
    x[(size_t)node * 64 + lane] = res;
  }
}

// ---- classifier: out = relu(x@Wc1+bc1)@Wc2+bc2  (K=64->64->32, fused) ----
__global__ void __launch_bounds__(256) classifier_k(const float* __restrict__ x,
    const float* __restrict__ Wc1, const float* __restrict__ bc1,
    const float* __restrict__ Wc2, const float* __restrict__ bc2,
    float* __restrict__ out, int n) {
  int lane = threadIdx.x & 63;
  int j2   = lane & 31;
  int wid  = (blockIdx.x * blockDim.x + threadIdx.x) >> 6;
  int nw   = (gridDim.x * blockDim.x) >> 6;
  float w1[64], w2[64];
#pragma unroll
  for (int k = 0; k < 64; ++k) w1[k] = Wc1[k * 64 + lane];
#pragma unroll
  for (int k = 0; k < 64; ++k) w2[k] = Wc2[k * 32 + j2];
  float b1v = bc1[lane], b2v = bc2[j2];
  for (int row = wid; row < n; row += nw) {
    float a = x[(size_t)row * 64 + lane];
    float t = b1v;
#pragma unroll
    for (int k = 0; k < 64; ++k) t = fmaf(rl(a, k), w1[k], t);
    t = fmaxf(t, 0.0f);
    float o = b2v;
#pragma unroll
    for (int k = 0; k < 64; ++k) o = fmaf(rl(t, k), w2[k], o);
    if (lane < 32) out[(size_t)row * 32 + lane] = o;
  }
}

// ---- per-graph mean readout; all_batch sorted -> binary search per graph ----
__global__ void __launch_bounds__(256) readout_k(const float* __restrict__ xc,
    const int* __restrict__ batch, int n, float* __restrict__ out) {
  __shared__ float part[8][32];
  int g  = blockIdx.x;
  int lo = lower_bound_i(batch, n, g);
  int hi = lower_bound_i(batch, n, g + 1);
  int j = threadIdx.x & 31, r = threadIdx.x >> 5;
  float acc = 0.0f;
  for (int i = lo + r; i < hi; i += 8) acc += xc[(size_t)i * 32 + j];
  part[r][j] = acc;
  __syncthreads();
  if (threadIdx.x < 32) {
    float s = 0.0f;
#pragma unroll
    for (int rr = 0; rr < 8; ++rr) s += part[rr][j];
    out[g * 32 + j] = (hi > lo) ? s / (float)(hi - lo) : 0.0f;
  }
}

extern "C" void kernel_launch(void* const* d_in, const int* in_sizes, int n_in,
                              void* d_out, int out_size, void* d_ws, size_t ws_size,
                              hipStream_t stream) {
  const float* X    = (const float*)d_in[0];
  const int*   src  = (const int*)d_in[1];
  const int*   dst  = (const int*)d_in[2];
  const int*   batch= (const int*)d_in[3];
  const float* W_in = (const float*)d_in[4];
  const float* b_in = (const float*)d_in[5];
  const float* W1a  = (const float*)d_in[6];
  const float* b1a  = (const float*)d_in[7];
  const float* W1b  = (const float*)d_in[8];
  const float* b1b  = (const float*)d_in[9];
  const float* W2   = (const float*)d_in[10];
  const float* b2   = (const float*)d_in[11];
  const float* W3   = (const float*)d_in[12];
  const float* b3   = (const float*)d_in[13];
  const float* Wc1  = (const float*)d_in[14];
  const float* bc1  = (const float*)d_in[15];
  const float* Wc2  = (const float*)d_in[16];
  const float* bc2  = (const float*)d_in[17];
  float* out = (float*)d_out;

  const int n = N_NODES, e = N_EDGES, nnz = NNZ_C;

  float* p    = (float*)d_ws;
  float* x    = p; p += (size_t)n * 64;   // 25.6 MB
  float* x0   = p; p += (size_t)n * 64;   // 25.6 MB
  float* h    = p; p += (size_t)n * 64;   // 25.6 MB
  float* Xe   = p; p += (size_t)e * 64;   // 12.8 MB (also reused as N x 32 classifier out)
  float* cntE = p; p += e;
  float* invE = p; p += e;

  hipMemsetAsync(cntE, 0, (size_t)e * sizeof(float), stream);
  count_edges_k<<<(nnz + 255) / 256, 256, 0, stream>>>(dst, cntE, nnz);
  inv_k<<<(e + 255) / 256, 256, 0, stream>>>(cntE, invE, e);

  mm_in_k<<<1024, 256, 0, stream>>>(X, W_in, b_in, x, x0, n);

  for (int l = 0; l < 2; ++l) {
    mm64_k<true ><<<2048, 256, 0, stream>>>(x, W1a, b1a, h, n);
    mm64_k<false><<<2048, 256, 0, stream>>>(h, W1b, b1b, h, n);  // in-place
    hipMemsetAsync(Xe, 0, (size_t)e * 64 * sizeof(float), stream);
    scatter_ve_k<<<(int)(((size_t)nnz * 64 + 255) / 256), 256, 0, stream>>>(h, src, dst, Xe, nnz);
    e2v_catmm_k<<<2048, 256, 0, stream>>>(Xe, invE, src, dst, x, x0, W2, b2, nnz, n);
    mm64_k<true ><<<2048, 256, 0, stream>>>(x, W3, b3, x, n);    // in-place
  }

  classifier_k<<<2048, 256, 0, stream>>>(x, Wc1, bc1, Wc2, bc2, Xe, n);
  readout_k<<<NGRAPH, 256, 0, stream>>>(Xe, batch, n, out);
}

// Round 2
// 1036.995 us; speedup vs baseline: 2.2375x; 2.2375x over previous
//
#include <hip/hip_runtime.h>

// EquivSetGNN forward, MI355X, all f32.
// R2: zero f32 atomics. CSR-by-dst built per call (int scan+fill); both V->E and
// E->V are pull-based. Per-node binary search hoisted into a one-shot row_off
// kernel. Gather kernels are lean (high occupancy) with 4-way unrolled
// independent gathers; matmul kernels are grid-stride with weights held in VGPRs
// (no branch around the matmul so the compiler can't sink the weight loads).

constexpr int NN = 100000;   // nodes
constexpr int NE = 50000;    // hyperedges
constexpr int NZ = 1280000;  // incidences
constexpr int NG = 256;      // graphs

__device__ __forceinline__ float rl(float v, int k) {
  return __int_as_float(__builtin_amdgcn_readlane(__float_as_int(v), k));
}

__device__ __forceinline__ int lbound(const int* a, int n, int v) {
  int lo = 0, hi = n;
  while (lo < hi) { int m = (lo + hi) >> 1; if (a[m] < v) lo = m + 1; else hi = m; }
  return lo;
}

// ---- CSR-by-dst build ----
__global__ void count_k(const int* __restrict__ dst, int* __restrict__ cnt, int nnz) {
  int i = blockIdx.x * blockDim.x + threadIdx.x;
  if (i < nnz) atomicAdd(&cnt[dst[i]], 1);
}

// exclusive scan of cnt -> off, cursor; invE = 1/max(cnt,1). One block, 256 thr.
__global__ void scan_k(const int* __restrict__ cnt, int* __restrict__ off,
                       int* __restrict__ cursor, float* __restrict__ invE, int e) {
  __shared__ int part[256];
  int t = threadIdx.x;
  int L = (e + 255) / 256;
  int lo = t * L, hi = min(lo + L, e);
  int s = 0;
  for (int i = lo; i < hi; ++i) s += cnt[i];
  part[t] = s;
  __syncthreads();
  if (t == 0) { int run = 0; for (int i = 0; i < 256; ++i) { int v = part[i]; part[i] = run; run += v; } }
  __syncthreads();
  int run = part[t];
  for (int i = lo; i < hi; ++i) {
    off[i] = run; cursor[i] = run;
    invE[i] = 1.0f / (float)max(cnt[i], 1);
    run += cnt[i];
  }
}

__global__ void fill_k(const int* __restrict__ src, const int* __restrict__ dst,
                       int* __restrict__ cursor, int* __restrict__ csr, int nnz) {
  int i = blockIdx.x * blockDim.x + threadIdx.x;
  if (i < nnz) { int p = atomicAdd(&cursor[dst[i]], 1); csr[p] = src[i]; }
}

// row offsets for sorted src: roff[v] = lower_bound(src, v), v in [0, n]
__global__ void rowoff_k(const int* __restrict__ src, int* __restrict__ roff, int n, int nnz) {
  int v = blockIdx.x * blockDim.x + threadIdx.x;
  if (v <= n) roff[v] = lbound(src, nnz, v);
}

// ---- x = relu(X @ W_in + b_in); copy to x0. K=128 ----
__global__ void __launch_bounds__(256) mm_in_k(const float* __restrict__ A,
    const float* __restrict__ W, const float* __restrict__ b,
    float* __restrict__ C, float* __restrict__ C2, int n) {
  int lane = threadIdx.x & 63;
  int wid = (blockIdx.x * blockDim.x + threadIdx.x) >> 6;
  int nw = (gridDim.x * blockDim.x) >> 6;
  float w[128];
#pragma unroll
  for (int k = 0; k < 128; ++k) w[k] = W[k * 64 + lane];
  float bb = b[lane];
  for (int row = wid; row < n; row += nw) {
    float alo = A[(size_t)row * 128 + lane];
    float ahi = A[(size_t)row * 128 + 64 + lane];
    float acc = bb;
#pragma unroll
    for (int k = 0; k < 64; ++k) acc = fmaf(rl(alo, k), w[k], acc);
#pragma unroll
    for (int k = 0; k < 64; ++k) acc = fmaf(rl(ahi, k), w[64 + k], acc);
    acc = fmaxf(acc, 0.0f);
    C[(size_t)row * 64 + lane] = acc;
    C2[(size_t)row * 64 + lane] = acc;
  }
}

// ---- h = relu(x@W1a+b1a)@W1b + b1b  (fused pair, K=64 each) ----
__global__ void __launch_bounds__(256) mm_dual_k(const float* __restrict__ x,
    const float* __restrict__ W1a, const float* __restrict__ b1a,
    const float* __restrict__ W1b, const float* __restrict__ b1b,
    float* __restrict__ h, int n) {
  int lane = threadIdx.x & 63;
  int wid = (blockIdx.x * blockDim.x + threadIdx.x) >> 6;
  int nw = (gridDim.x * blockDim.x) >> 6;
  float wa[64], wb[64];
#pragma unroll
  for (int k = 0; k < 64; ++k) wa[k] = W1a[k * 64 + lane];
#pragma unroll
  for (int k = 0; k < 64; ++k) wb[k] = W1b[k * 64 + lane];
  float ba = b1a[lane], bbv = b1b[lane];
  for (int row = wid; row < n; row += nw) {
    float a = x[(size_t)row * 64 + lane];
    float t = ba;
#pragma unroll
    for (int k = 0; k < 64; ++k) t = fmaf(rl(a, k), wa[k], t);
    t = fmaxf(t, 0.0f);
    float o = bbv;
#pragma unroll
    for (int k = 0; k < 64; ++k) o = fmaf(rl(t, k), wb[k], o);
    h[(size_t)row * 64 + lane] = o;
  }
}

// ---- C = [relu](A @ W + b); K=64; in-place safe ----
template <bool RELU>
__global__ void __launch_bounds__(256) mm64_k(const float* A,
    const float* __restrict__ W, const float* __restrict__ b, float* C, int n) {
  int lane = threadIdx.x & 63;
  int wid = (blockIdx.x * blockDim.x + threadIdx.x) >> 6;
  int nw = (gridDim.x * blockDim.x) >> 6;
  float w[64];
#pragma unroll
  for (int k = 0; k < 64; ++k) w[k] = W[k * 64 + lane];
  float bb = b[lane];
  for (int row = wid; row < n; row += nw) {
    float a = A[(size_t)row * 64 + lane];
    float acc = bb;
#pragma unroll
    for (int k = 0; k < 64; ++k) acc = fmaf(rl(a, k), w[k], acc);
    if (RELU) acc = fmaxf(acc, 0.0f);
    C[(size_t)row * 64 + lane] = acc;
  }
}

// ---- V->E pull: Xe[e] = invE[e] * sum_{i in csr[e]} h[i]  (wave per edge) ----
__global__ void __launch_bounds__(256) ve_pull_k(const float* __restrict__ h,
    const int* __restrict__ csr, const int* __restrict__ off, const int* __restrict__ cnt,
    const float* __restrict__ invE, float* __restrict__ Xe, int e) {
  int lane = threadIdx.x & 63;
  int w = (blockIdx.x * blockDim.x + threadIdx.x) >> 6;
  if (w >= e) return;
  int lo = off[w], end = lo + cnt[w];
  float s0 = 0, s1 = 0, s2 = 0, s3 = 0;
  int i = lo;
  for (; i + 4 <= end; i += 4) {
    int e0 = csr[i], e1 = csr[i + 1], e2 = csr[i + 2], e3 = csr[i + 3];
    s0 += h[(size_t)e0 * 64 + lane];
    s1 += h[(size_t)e1 * 64 + lane];
    s2 += h[(size_t)e2 * 64 + lane];
    s3 += h[(size_t)e3 * 64 + lane];
  }
  for (; i < end; ++i) s0 += h[(size_t)csr[i] * 64 + lane];
  Xe[(size_t)w * 64 + lane] = ((s0 + s1) + (s2 + s3)) * invE[w];
}

// ---- E->V pull: z[v] = mean_{i in [roff[v],roff[v+1])} Xe[dst[i]] (wave per node) ----
__global__ void __launch_bounds__(256) zgather_k(const float* __restrict__ Xe,
    const int* __restrict__ dstArr, const int* __restrict__ roff,
    float* __restrict__ z, int n) {
  int lane = threadIdx.x & 63;
  int w = (blockIdx.x * blockDim.x + threadIdx.x) >> 6;
  if (w >= n) return;
  int lo = roff[w], hi = roff[w + 1];
  float s0 = 0, s1 = 0, s2 = 0, s3 = 0;
  int i = lo;
  for (; i + 4 <= hi; i += 4) {
    int e0 = dstArr[i], e1 = dstArr[i + 1], e2 = dstArr[i + 2], e3 = dstArr[i + 3];
    s0 += Xe[(size_t)e0 * 64 + lane];
    s1 += Xe[(size_t)e1 * 64 + lane];
    s2 += Xe[(size_t)e2 * 64 + lane];
    s3 += Xe[(size_t)e3 * 64 + lane];
  }
  for (; i < hi; ++i) s0 += Xe[(size_t)dstArr[i] * 64 + lane];
  float s = (s0 + s1) + (s2 + s3);
  z[(size_t)w * 64 + lane] = (hi > lo) ? s / (float)(hi - lo) : 0.0f;
}

// ---- x = 0.5*x0 + 0.5*(cat(x, z)@W2 + b2)  (masked for deg==0; no branch) ----
__global__ void __launch_bounds__(256) catmm_k(float* x, const float* __restrict__ z,
    const float* __restrict__ x0, const int* __restrict__ roff,
    const float* __restrict__ W2, const float* __restrict__ b2, int n) {
  int lane = threadIdx.x & 63;
  int wid = (blockIdx.x * blockDim.x + threadIdx.x) >> 6;
  int nw = (gridDim.x * blockDim.x) >> 6;
  float w[128];
#pragma unroll
  for (int k = 0; k < 128; ++k) w[k] = W2[k * 64 + lane];
  float bb = b2[lane];
  for (int row = wid; row < n; row += nw) {
    float a = x[(size_t)row * 64 + lane];
    float zz = z[(size_t)row * 64 + lane];
    int deg = roff[row + 1] - roff[row];
    float acc = bb;
#pragma unroll
    for (int k = 0; k < 64; ++k) acc = fmaf(rl(a, k), w[k], acc);
#pragma unroll
    for (int k = 0; k < 64; ++k) acc = fmaf(rl(zz, k), w[64 + k], acc);
    float res = 0.5f * x0[(size_t)row * 64 + lane];
    res = (deg > 0) ? fmaf(0.5f, acc, res) : res;
    x[(size_t)row * 64 + lane] = res;
  }
}

// ---- classifier: out = relu(x@Wc1+bc1)@Wc2+bc2 ----
__global__ void __launch_bounds__(256) classifier_k(const float* __restrict__ x,
    const float* __restrict__ Wc1, const float* __restrict__ bc1,
    const float* __restrict__ Wc2, const float* __restrict__ bc2,
    float* __restrict__ out, int n) {
  int lane = threadIdx.x & 63;
  int j2 = lane & 31;
  int wid = (blockIdx.x * blockDim.x + threadIdx.x) >> 6;
  int nw = (gridDim.x * blockDim.x) >> 6;
  float w1[64], w2[64];
#pragma unroll
  for (int k = 0; k < 64; ++k) w1[k] = Wc1[k * 64 + lane];
#pragma unroll
  for (int k = 0; k < 64; ++k) w2[k] = Wc2[k * 32 + j2];
  float b1v = bc1[lane], b2v = bc2[j2];
  for (int row = wid; row < n; row += nw) {
    float a = x[(size_t)row * 64 + lane];
    float t = b1v;
#pragma unroll
    for (int k = 0; k < 64; ++k) t = fmaf(rl(a, k), w1[k], t);
    t = fmaxf(t, 0.0f);
    float o = b2v;
#pragma unroll
    for (int k = 0; k < 64; ++k) o = fmaf(rl(t, k), w2[k], o);
    if (lane < 32) out[(size_t)row * 32 + lane] = o;
  }
}

// ---- per-graph mean readout over sorted batch ids ----
__global__ void __launch_bounds__(256) readout_k(const float* __restrict__ xc,
    const int* __restrict__ batch, int n, float* __restrict__ out) {
  __shared__ float part[8][32];
  int g = blockIdx.x;
  int lo = lbound(batch, n, g);
  int hi = lbound(batch, n, g + 1);
  int j = threadIdx.x & 31, r = threadIdx.x >> 5;
  float acc = 0.0f;
  for (int i = lo + r; i < hi; i += 8) acc += xc[(size_t)i * 32 + j];
  part[r][j] = acc;
  __syncthreads();
  if (threadIdx.x < 32) {
    float s = 0.0f;
#pragma unroll
    for (int rr = 0; rr < 8; ++rr) s += part[rr][j];
    out[g * 32 + j] = (hi > lo) ? s / (float)(hi - lo) : 0.0f;
  }
}

extern "C" void kernel_launch(void* const* d_in, const int* in_sizes, int n_in,
                              void* d_out, int out_size, void* d_ws, size_t ws_size,
                              hipStream_t stream) {
  const float* X    = (const float*)d_in[0];
  const int*   src  = (const int*)d_in[1];
  const int*   dst  = (const int*)d_in[2];
  const int*   batch= (const int*)d_in[3];
  const float* W_in = (const float*)d_in[4];
  const float* b_in = (const float*)d_in[5];
  const float* W1a  = (const float*)d_in[6];
  const float* b1a  = (const float*)d_in[7];
  const float* W1b  = (const float*)d_in[8];
  const float* b1b  = (const float*)d_in[9];
  const float* W2   = (const float*)d_in[10];
  const float* b2   = (const float*)d_in[11];
  const float* W3   = (const float*)d_in[12];
  const float* b3   = (const float*)d_in[13];
  const float* Wc1  = (const float*)d_in[14];
  const float* bc1  = (const float*)d_in[15];
  const float* Wc2  = (const float*)d_in[16];
  const float* bc2  = (const float*)d_in[17];
  float* out = (float*)d_out;

  // workspace layout (~96 MB)
  float* p  = (float*)d_ws;
  float* x  = p; p += (size_t)NN * 64;  // 25.6 MB
  float* x0 = p; p += (size_t)NN * 64;  // 25.6 MB
  float* h  = p; p += (size_t)NN * 64;  // 25.6 MB (aliased as z after ve_pull consumes it)
  float* Xe = p; p += (size_t)NE * 64;  // 12.8 MB (reused as N x 32 classifier out)
  float* invE = p; p += NE;
  int* q     = (int*)p;
  int* cnt   = q; q += NE;
  int* off   = q; q += NE;
  int* cursor= q; q += NE;
  int* roff  = q; q += NN + 1;
  int* csr   = q; q += NZ;              // 5.12 MB
  float* z = h;                          // alias: h consumed by ve_pull before zgather writes z

  // CSR-by-dst + row offsets (once per call)
  hipMemsetAsync(cnt, 0, (size_t)NE * sizeof(int), stream);
  count_k<<<(NZ + 255) / 256, 256, 0, stream>>>(dst, cnt, NZ);
  scan_k<<<1, 256, 0, stream>>>(cnt, off, cursor, invE, NE);
  fill_k<<<(NZ + 255) / 256, 256, 0, stream>>>(src, dst, cursor, csr, NZ);
  rowoff_k<<<(NN + 256) / 256, 256, 0, stream>>>(src, roff, NN, NZ);

  mm_in_k<<<1024, 256, 0, stream>>>(X, W_in, b_in, x, x0, NN);

  for (int l = 0; l < 2; ++l) {
    mm_dual_k<<<2048, 256, 0, stream>>>(x, W1a, b1a, W1b, b1b, h, NN);
    ve_pull_k<<<(NE + 3) / 4, 256, 0, stream>>>(h, csr, off, cnt, invE, Xe, NE);
    zgather_k<<<(NN + 3) / 4, 256, 0, stream>>>(Xe, dst, roff, z, NN);
    catmm_k<<<2048, 256, 0, stream>>>(x, z, x0, roff, W2, b2, NN);
    mm64_k<true><<<2048, 256, 0, stream>>>(x, W3, b3, x, NN);  // in-place
  }

  classifier_k<<<2048, 256, 0, stream>>>(x, Wc1, bc1, Wc2, bc2, Xe, NN);
  readout_k<<<NG, 256, 0, stream>>>(Xe, batch, NN, out);
}

// Round 3
// 894.715 us; speedup vs baseline: 2.5934x; 1.1590x over previous
//
#include <hip/hip_runtime.h>

// EquivSetGNN forward, MI355X, all f32.
// R3: parallel CSR scan (was 150us single-block), diff-based row offsets
// (was 100k binary searches), catmm+W3 fused (saves 51MB x round-trip/layer),
// gathers 8-way unrolled.

constexpr int NN = 100000;   // nodes
constexpr int NE = 50000;    // hyperedges
constexpr int NZ = 1280000;  // incidences
constexpr int NG = 256;      // graphs
constexpr int NB = (NE + 255) / 256;  // scan blocks = 196

__device__ __forceinline__ float rl(float v, int k) {
  return __int_as_float(__builtin_amdgcn_readlane(__float_as_int(v), k));
}

__device__ __forceinline__ int lbound(const int* a, int n, int v) {
  int lo = 0, hi = n;
  while (lo < hi) { int m = (lo + hi) >> 1; if (a[m] < v) lo = m + 1; else hi = m; }
  return lo;
}

// ---- CSR-by-dst build ----
__global__ void count_k(const int* __restrict__ dst, int* __restrict__ cnt, int nnz) {
  int i = blockIdx.x * blockDim.x + threadIdx.x;
  if (i < nnz) atomicAdd(&cnt[dst[i]], 1);
}

// block sums of cnt (256/block)
__global__ void bsum_k(const int* __restrict__ cnt, int* __restrict__ bsum, int e) {
  __shared__ int red[256];
  int i = blockIdx.x * 256 + threadIdx.x;
  red[threadIdx.x] = (i < e) ? cnt[i] : 0;
  __syncthreads();
  for (int s = 128; s > 0; s >>= 1) {
    if (threadIdx.x < s) red[threadIdx.x] += red[threadIdx.x + s];
    __syncthreads();
  }
  if (threadIdx.x == 0) bsum[blockIdx.x] = red[0];
}

// exclusive scan of bsum in place (nb <= 256), one block
__global__ void bscan_k(int* __restrict__ bsum, int nb) {
  __shared__ int sh[256];
  int t = threadIdx.x;
  int my = (t < nb) ? bsum[t] : 0;
  sh[t] = my;
  __syncthreads();
  for (int ofs = 1; ofs < 256; ofs <<= 1) {
    int v = (t >= ofs) ? sh[t - ofs] : 0;
    __syncthreads();
    sh[t] += v;
    __syncthreads();
  }
  if (t < nb) bsum[t] = sh[t] - my;  // exclusive
}

// per-block exclusive scan + add block prefix; write off/cursor/invE
__global__ void csroff_k(const int* __restrict__ cnt, const int* __restrict__ bsum,
                         int* __restrict__ off, int* __restrict__ cursor,
                         float* __restrict__ invE, int e) {
  __shared__ int sh[256];
  int t = threadIdx.x;
  int i = blockIdx.x * 256 + t;
  int c = (i < e) ? cnt[i] : 0;
  sh[t] = c;
  __syncthreads();
  for (int ofs = 1; ofs < 256; ofs <<= 1) {
    int v = (t >= ofs) ? sh[t - ofs] : 0;
    __syncthreads();
    sh[t] += v;
    __syncthreads();
  }
  int excl = sh[t] - c + bsum[blockIdx.x];
  if (i < e) {
    off[i] = excl;
    cursor[i] = excl;
    invE[i] = 1.0f / (float)max(c, 1);
  }
}

__global__ void fill_k(const int* __restrict__ src, const int* __restrict__ dst,
                       int* __restrict__ cursor, int* __restrict__ csr, int nnz) {
  int i = blockIdx.x * blockDim.x + threadIdx.x;
  if (i < nnz) { int p = atomicAdd(&cursor[dst[i]], 1); csr[p] = src[i]; }
}

// roff from sorted src via adjacent-diff (src[i] in [0,n))
__global__ void rowoff_diff_k(const int* __restrict__ src, int* __restrict__ roff,
                              int n, int nnz) {
  int i = blockIdx.x * blockDim.x + threadIdx.x;
  if (i >= nnz) return;
  int s = src[i];
  int prev = (i == 0) ? -1 : src[i - 1];
  for (int v = prev + 1; v <= s; ++v) roff[v] = i;
  if (i == nnz - 1) {
    for (int v = s + 1; v <= n; ++v) roff[v] = nnz;
  }
}

// ---- x = relu(X @ W_in + b_in); copy to x0. K=128 ----
__global__ void __launch_bounds__(256) mm_in_k(const float* __restrict__ A,
    const float* __restrict__ W, const float* __restrict__ b,
    float* __restrict__ C, float* __restrict__ C2, int n) {
  int lane = threadIdx.x & 63;
  int wid = (blockIdx.x * blockDim.x + threadIdx.x) >> 6;
  int nw = (gridDim.x * blockDim.x) >> 6;
  float w[128];
#pragma unroll
  for (int k = 0; k < 128; ++k) w[k] = W[k * 64 + lane];
  float bb = b[lane];
  for (int row = wid; row < n; row += nw) {
    float alo = A[(size_t)row * 128 + lane];
    float ahi = A[(size_t)row * 128 + 64 + lane];
    float acc = bb;
#pragma unroll
    for (int k = 0; k < 64; ++k) acc = fmaf(rl(alo, k), w[k], acc);
#pragma unroll
    for (int k = 0; k < 64; ++k) acc = fmaf(rl(ahi, k), w[64 + k], acc);
    acc = fmaxf(acc, 0.0f);
    C[(size_t)row * 64 + lane] = acc;
    C2[(size_t)row * 64 + lane] = acc;
  }
}

// ---- h = relu(x@W1a+b1a)@W1b + b1b  (fused pair, K=64 each) ----
__global__ void __launch_bounds__(256) mm_dual_k(const float* __restrict__ x,
    const float* __restrict__ W1a, const float* __restrict__ b1a,
    const float* __restrict__ W1b, const float* __restrict__ b1b,
    float* __restrict__ h, int n) {
  int lane = threadIdx.x & 63;
  int wid = (blockIdx.x * blockDim.x + threadIdx.x) >> 6;
  int nw = (gridDim.x * blockDim.x) >> 6;
  float wa[64], wb[64];
#pragma unroll
  for (int k = 0; k < 64; ++k) wa[k] = W1a[k * 64 + lane];
#pragma unroll
  for (int k = 0; k < 64; ++k) wb[k] = W1b[k * 64 + lane];
  float ba = b1a[lane], bbv = b1b[lane];
  for (int row = wid; row < n; row += nw) {
    float a = x[(size_t)row * 64 + lane];
    float t = ba;
#pragma unroll
    for (int k = 0; k < 64; ++k) t = fmaf(rl(a, k), wa[k], t);
    t = fmaxf(t, 0.0f);
    float o = bbv;
#pragma unroll
    for (int k = 0; k < 64; ++k) o = fmaf(rl(t, k), wb[k], o);
    h[(size_t)row * 64 + lane] = o;
  }
}

// ---- V->E pull: Xe[e] = invE[e] * sum_{i in csr[e]} h[i]  (wave per edge) ----
__global__ void __launch_bounds__(256) ve_pull_k(const float* __restrict__ h,
    const int* __restrict__ csr, const int* __restrict__ off, const int* __restrict__ cnt,
    const float* __restrict__ invE, float* __restrict__ Xe, int e) {
  int lane = threadIdx.x & 63;
  int w = (blockIdx.x * blockDim.x + threadIdx.x) >> 6;
  if (w >= e) return;
  int lo = off[w], end = lo + cnt[w];
  float s0 = 0, s1 = 0, s2 = 0, s3 = 0, s4 = 0, s5 = 0, s6 = 0, s7 = 0;
  int i = lo;
  for (; i + 8 <= end; i += 8) {
    int e0 = csr[i], e1 = csr[i + 1], e2 = csr[i + 2], e3 = csr[i + 3];
    int e4 = csr[i + 4], e5 = csr[i + 5], e6 = csr[i + 6], e7 = csr[i + 7];
    s0 += h[(size_t)e0 * 64 + lane];
    s1 += h[(size_t)e1 * 64 + lane];
    s2 += h[(size_t)e2 * 64 + lane];
    s3 += h[(size_t)e3 * 64 + lane];
    s4 += h[(size_t)e4 * 64 + lane];
    s5 += h[(size_t)e5 * 64 + lane];
    s6 += h[(size_t)e6 * 64 + lane];
    s7 += h[(size_t)e7 * 64 + lane];
  }
  for (; i < end; ++i) s0 += h[(size_t)csr[i] * 64 + lane];
  float s = ((s0 + s1) + (s2 + s3)) + ((s4 + s5) + (s6 + s7));
  Xe[(size_t)w * 64 + lane] = s * invE[w];
}

// ---- E->V pull: z[v] = mean_{i in [roff[v],roff[v+1])} Xe[dst[i]] (wave per node) ----
__global__ void __launch_bounds__(256) zgather_k(const float* __restrict__ Xe,
    const int* __restrict__ dstArr, const int* __restrict__ roff,
    float* __restrict__ z, int n) {
  int lane = threadIdx.x & 63;
  int w = (blockIdx.x * blockDim.x + threadIdx.x) >> 6;
  if (w >= n) return;
  int lo = roff[w], hi = roff[w + 1];
  float s0 = 0, s1 = 0, s2 = 0, s3 = 0, s4 = 0, s5 = 0, s6 = 0, s7 = 0;
  int i = lo;
  for (; i + 8 <= hi; i += 8) {
    int e0 = dstArr[i], e1 = dstArr[i + 1], e2 = dstArr[i + 2], e3 = dstArr[i + 3];
    int e4 = dstArr[i + 4], e5 = dstArr[i + 5], e6 = dstArr[i + 6], e7 = dstArr[i + 7];
    s0 += Xe[(size_t)e0 * 64 + lane];
    s1 += Xe[(size_t)e1 * 64 + lane];
    s2 += Xe[(size_t)e2 * 64 + lane];
    s3 += Xe[(size_t)e3 * 64 + lane];
    s4 += Xe[(size_t)e4 * 64 + lane];
    s5 += Xe[(size_t)e5 * 64 + lane];
    s6 += Xe[(size_t)e6 * 64 + lane];
    s7 += Xe[(size_t)e7 * 64 + lane];
  }
  for (; i < hi; ++i) s0 += Xe[(size_t)dstArr[i] * 64 + lane];
  float s = ((s0 + s1) + (s2 + s3)) + ((s4 + s5) + (s6 + s7));
  z[(size_t)w * 64 + lane] = (hi > lo) ? s / (float)(hi - lo) : 0.0f;
}

// ---- fused: res = 0.5*x0 + 0.5*(cat(x,z)@W2+b2) [masked]; x = relu(res@W3+b3) ----
__global__ void __launch_bounds__(256) catmm_w3_k(float* x, const float* __restrict__ z,
    const float* __restrict__ x0, const int* __restrict__ roff,
    const float* __restrict__ W2, const float* __restrict__ b2,
    const float* __restrict__ W3, const float* __restrict__ b3, int n) {
  int lane = threadIdx.x & 63;
  int wid = (blockIdx.x * blockDim.x + threadIdx.x) >> 6;
  int nw = (gridDim.x * blockDim.x) >> 6;
  float w2r[128], w3r[64];
#pragma unroll
  for (int k = 0; k < 128; ++k) w2r[k] = W2[k * 64 + lane];
#pragma unroll
  for (int k = 0; k < 64; ++k) w3r[k] = W3[k * 64 + lane];
  float bb2 = b2[lane], bb3 = b3[lane];
  for (int row = wid; row < n; row += nw) {
    float a   = x[(size_t)row * 64 + lane];
    float zz  = z[(size_t)row * 64 + lane];
    float x0v = x0[(size_t)row * 64 + lane];
    int deg = roff[row + 1] - roff[row];
    float acc = bb2;
#pragma unroll
    for (int k = 0; k < 64; ++k) acc = fmaf(rl(a, k), w2r[k], acc);
#pragma unroll
    for (int k = 0; k < 64; ++k) acc = fmaf(rl(zz, k), w2r[64 + k], acc);
    float res = 0.5f * x0v;
    res = (deg > 0) ? fmaf(0.5f, acc, res) : res;
    float o = bb3;
#pragma unroll
    for (int k = 0; k < 64; ++k) o = fmaf(rl(res, k), w3r[k], o);
    x[(size_t)row * 64 + lane] = fmaxf(o, 0.0f);
  }
}

// ---- classifier: out = relu(x@Wc1+bc1)@Wc2+bc2 ----
__global__ void __launch_bounds__(256) classifier_k(const float* __restrict__ x,
    const float* __restrict__ Wc1, const float* __restrict__ bc1,
    const float* __restrict__ Wc2, const float* __restrict__ bc2,
    float* __restrict__ out, int n) {
  int lane = threadIdx.x & 63;
  int j2 = lane & 31;
  int wid = (blockIdx.x * blockDim.x + threadIdx.x) >> 6;
  int nw = (gridDim.x * blockDim.x) >> 6;
  float w1[64], w2[64];
#pragma unroll
  for (int k = 0; k < 64; ++k) w1[k] = Wc1[k * 64 + lane];
#pragma unroll
  for (int k = 0; k < 64; ++k) w2[k] = Wc2[k * 32 + j2];
  float b1v = bc1[lane], b2v = bc2[j2];
  for (int row = wid; row < n; row += nw) {
    float a = x[(size_t)row * 64 + lane];
    float t = b1v;
#pragma unroll
    for (int k = 0; k < 64; ++k) t = fmaf(rl(a, k), w1[k], t);
    t = fmaxf(t, 0.0f);
    float o = b2v;
#pragma unroll
    for (int k = 0; k < 64; ++k) o = fmaf(rl(t, k), w2[k], o);
    if (lane < 32) out[(size_t)row * 32 + lane] = o;
  }
}

// ---- per-graph mean readout over sorted batch ids ----
__global__ void __launch_bounds__(256) readout_k(const float* __restrict__ xc,
    const int* __restrict__ batch, int n, float* __restrict__ out) {
  __shared__ float part[8][32];
  int g = blockIdx.x;
  int lo = lbound(batch, n, g);
  int hi = lbound(batch, n, g + 1);
  int j = threadIdx.x & 31, r = threadIdx.x >> 5;
  float acc = 0.0f;
  for (int i = lo + r; i < hi; i += 8) acc += xc[(size_t)i * 32 + j];
  part[r][j] = acc;
  __syncthreads();
  if (threadIdx.x < 32) {
    float s = 0.0f;
#pragma unroll
    for (int rr = 0; rr < 8; ++rr) s += part[rr][j];
    out[g * 32 + j] = (hi > lo) ? s / (float)(hi - lo) : 0.0f;
  }
}

extern "C" void kernel_launch(void* const* d_in, const int* in_sizes, int n_in,
                              void* d_out, int out_size, void* d_ws, size_t ws_size,
                              hipStream_t stream) {
  const float* X    = (const float*)d_in[0];
  const int*   src  = (const int*)d_in[1];
  const int*   dst  = (const int*)d_in[2];
  const int*   batch= (const int*)d_in[3];
  const float* W_in = (const float*)d_in[4];
  const float* b_in = (const float*)d_in[5];
  const float* W1a  = (const float*)d_in[6];
  const float* b1a  = (const float*)d_in[7];
  const float* W1b  = (const float*)d_in[8];
  const float* b1b  = (const float*)d_in[9];
  const float* W2   = (const float*)d_in[10];
  const float* b2   = (const float*)d_in[11];
  const float* W3   = (const float*)d_in[12];
  const float* b3   = (const float*)d_in[13];
  const float* Wc1  = (const float*)d_in[14];
  const float* bc1  = (const float*)d_in[15];
  const float* Wc2  = (const float*)d_in[16];
  const float* bc2  = (const float*)d_in[17];
  float* out = (float*)d_out;

  // workspace layout (~96 MB)
  float* p  = (float*)d_ws;
  float* x  = p; p += (size_t)NN * 64;  // 25.6 MB
  float* x0 = p; p += (size_t)NN * 64;  // 25.6 MB
  float* h  = p; p += (size_t)NN * 64;  // 25.6 MB (aliased as z: h consumed by ve_pull first)
  float* Xe = p; p += (size_t)NE * 64;  // 12.8 MB (reused as N x 32 classifier out)
  float* invE = p; p += NE;
  int* q     = (int*)p;
  int* cnt   = q; q += NE;
  int* off   = q; q += NE;
  int* cursor= q; q += NE;
  int* roff  = q; q += NN + 1;
  int* csr   = q; q += NZ;              // 5.12 MB
  int* bsum  = q; q += 256;
  float* z = h;

  // CSR-by-dst + row offsets (once per call)
  hipMemsetAsync(cnt, 0, (size_t)NE * sizeof(int), stream);
  count_k<<<(NZ + 255) / 256, 256, 0, stream>>>(dst, cnt, NZ);
  bsum_k<<<NB, 256, 0, stream>>>(cnt, bsum, NE);
  bscan_k<<<1, 256, 0, stream>>>(bsum, NB);
  csroff_k<<<NB, 256, 0, stream>>>(cnt, bsum, off, cursor, invE, NE);
  fill_k<<<(NZ + 255) / 256, 256, 0, stream>>>(src, dst, cursor, csr, NZ);
  rowoff_diff_k<<<(NZ + 255) / 256, 256, 0, stream>>>(src, roff, NN, NZ);

  mm_in_k<<<1024, 256, 0, stream>>>(X, W_in, b_in, x, x0, NN);

  for (int l = 0; l < 2; ++l) {
    mm_dual_k<<<2048, 256, 0, stream>>>(x, W1a, b1a, W1b, b1b, h, NN);
    ve_pull_k<<<(NE + 3) / 4, 256, 0, stream>>>(h, csr, off, cnt, invE, Xe, NE);
    zgather_k<<<(NN + 3) / 4, 256, 0, stream>>>(Xe, dst, roff, z, NN);
    catmm_w3_k<<<2048, 256, 0, stream>>>(x, z, x0, roff, W2, b2, W3, b3, NN);
  }

  classifier_k<<<2048, 256, 0, stream>>>(x, Wc1, bc1, Wc2, bc2, Xe, NN);
  readout_k<<<NG, 256, 0, stream>>>(Xe, batch, NN, out);
}

// Round 4
// 860.837 us; speedup vs baseline: 2.6954x; 1.0394x over previous
//
#include <hip/hip_runtime.h>
#include <hip/hip_fp16.h>

// EquivSetGNN forward, MI355X.
// R4: h / Xe / z stored as fp16 (gather tables) -> halves the 327MB/layer gather
// traffic and staging writes. Error analysis: |h|~0.04, fp16 eps 4.9e-4, and each
// downstream matmul contracts error by sqrt(K)*sigma_w ~ 0.4 -> final ~1e-5 << 3.4e-4.
// x / x0 remain f32. CSR build unchanged (fill_k ~97us, write-amp limited).

constexpr int NN = 100000;   // nodes
constexpr int NE = 50000;    // hyperedges
constexpr int NZ = 1280000;  // incidences
constexpr int NG = 256;      // graphs
constexpr int NB = (NE + 255) / 256;  // scan blocks

__device__ __forceinline__ float rl(float v, int k) {
  return __int_as_float(__builtin_amdgcn_readlane(__float_as_int(v), k));
}

__device__ __forceinline__ int lbound(const int* a, int n, int v) {
  int lo = 0, hi = n;
  while (lo < hi) { int m = (lo + hi) >> 1; if (a[m] < v) lo = m + 1; else hi = m; }
  return lo;
}

// ---- CSR-by-dst build ----
__global__ void count_k(const int* __restrict__ dst, int* __restrict__ cnt, int nnz) {
  int i = blockIdx.x * blockDim.x + threadIdx.x;
  if (i < nnz) atomicAdd(&cnt[dst[i]], 1);
}

__global__ void bsum_k(const int* __restrict__ cnt, int* __restrict__ bsum, int e) {
  __shared__ int red[256];
  int i = blockIdx.x * 256 + threadIdx.x;
  red[threadIdx.x] = (i < e) ? cnt[i] : 0;
  __syncthreads();
  for (int s = 128; s > 0; s >>= 1) {
    if (threadIdx.x < s) red[threadIdx.x] += red[threadIdx.x + s];
    __syncthreads();
  }
  if (threadIdx.x == 0) bsum[blockIdx.x] = red[0];
}

__global__ void bscan_k(int* __restrict__ bsum, int nb) {
  __shared__ int sh[256];
  int t = threadIdx.x;
  int my = (t < nb) ? bsum[t] : 0;
  sh[t] = my;
  __syncthreads();
  for (int ofs = 1; ofs < 256; ofs <<= 1) {
    int v = (t >= ofs) ? sh[t - ofs] : 0;
    __syncthreads();
    sh[t] += v;
    __syncthreads();
  }
  if (t < nb) bsum[t] = sh[t] - my;  // exclusive
}

__global__ void csroff_k(const int* __restrict__ cnt, const int* __restrict__ bsum,
                         int* __restrict__ off, int* __restrict__ cursor,
                         float* __restrict__ invE, int e) {
  __shared__ int sh[256];
  int t = threadIdx.x;
  int i = blockIdx.x * 256 + t;
  int c = (i < e) ? cnt[i] : 0;
  sh[t] = c;
  __syncthreads();
  for (int ofs = 1; ofs < 256; ofs <<= 1) {
    int v = (t >= ofs) ? sh[t - ofs] : 0;
    __syncthreads();
    sh[t] += v;
    __syncthreads();
  }
  int excl = sh[t] - c + bsum[blockIdx.x];
  if (i < e) {
    off[i] = excl;
    cursor[i] = excl;
    invE[i] = 1.0f / (float)max(c, 1);
  }
}

__global__ void fill_k(const int* __restrict__ src, const int* __restrict__ dst,
                       int* __restrict__ cursor, int* __restrict__ csr, int nnz) {
  int i = blockIdx.x * blockDim.x + threadIdx.x;
  if (i < nnz) { int p = atomicAdd(&cursor[dst[i]], 1); csr[p] = src[i]; }
}

__global__ void rowoff_diff_k(const int* __restrict__ src, int* __restrict__ roff,
                              int n, int nnz) {
  int i = blockIdx.x * blockDim.x + threadIdx.x;
  if (i >= nnz) return;
  int s = src[i];
  int prev = (i == 0) ? -1 : src[i - 1];
  for (int v = prev + 1; v <= s; ++v) roff[v] = i;
  if (i == nnz - 1) {
    for (int v = s + 1; v <= n; ++v) roff[v] = nnz;
  }
}

// ---- x = relu(X @ W_in + b_in); copy to x0. K=128 ----
__global__ void __launch_bounds__(256) mm_in_k(const float* __restrict__ A,
    const float* __restrict__ W, const float* __restrict__ b,
    float* __restrict__ C, float* __restrict__ C2, int n) {
  int lane = threadIdx.x & 63;
  int wid = (blockIdx.x * blockDim.x + threadIdx.x) >> 6;
  int nw = (gridDim.x * blockDim.x) >> 6;
  float w[128];
#pragma unroll
  for (int k = 0; k < 128; ++k) w[k] = W[k * 64 + lane];
  float bb = b[lane];
  for (int row = wid; row < n; row += nw) {
    float alo = A[(size_t)row * 128 + lane];
    float ahi = A[(size_t)row * 128 + 64 + lane];
    float acc = bb;
#pragma unroll
    for (int k = 0; k < 64; ++k) acc = fmaf(rl(alo, k), w[k], acc);
#pragma unroll
    for (int k = 0; k < 64; ++k) acc = fmaf(rl(ahi, k), w[64 + k], acc);
    acc = fmaxf(acc, 0.0f);
    C[(size_t)row * 64 + lane] = acc;
    C2[(size_t)row * 64 + lane] = acc;
  }
}

// ---- h = relu(x@W1a+b1a)@W1b + b1b  (fp16 output) ----
__global__ void __launch_bounds__(256) mm_dual_k(const float* __restrict__ x,
    const float* __restrict__ W1a, const float* __restrict__ b1a,
    const float* __restrict__ W1b, const float* __restrict__ b1b,
    __half* __restrict__ h, int n) {
  int lane = threadIdx.x & 63;
  int wid = (blockIdx.x * blockDim.x + threadIdx.x) >> 6;
  int nw = (gridDim.x * blockDim.x) >> 6;
  float wa[64], wb[64];
#pragma unroll
  for (int k = 0; k < 64; ++k) wa[k] = W1a[k * 64 + lane];
#pragma unroll
  for (int k = 0; k < 64; ++k) wb[k] = W1b[k * 64 + lane];
  float ba = b1a[lane], bbv = b1b[lane];
  for (int row = wid; row < n; row += nw) {
    float a = x[(size_t)row * 64 + lane];
    float t = ba;
#pragma unroll
    for (int k = 0; k < 64; ++k) t = fmaf(rl(a, k), wa[k], t);
    t = fmaxf(t, 0.0f);
    float o = bbv;
#pragma unroll
    for (int k = 0; k < 64; ++k) o = fmaf(rl(t, k), wb[k], o);
    h[(size_t)row * 64 + lane] = __float2half(o);
  }
}

// ---- V->E pull: Xe[e] = invE[e] * sum h[csr[...]]  (fp16 in/out) ----
__global__ void __launch_bounds__(256) ve_pull_k(const __half* __restrict__ h,
    const int* __restrict__ csr, const int* __restrict__ off, const int* __restrict__ cnt,
    const float* __restrict__ invE, __half* __restrict__ Xe, int e) {
  int lane = threadIdx.x & 63;
  int w = (blockIdx.x * blockDim.x + threadIdx.x) >> 6;
  if (w >= e) return;
  int lo = off[w], end = lo + cnt[w];
  float s0 = 0, s1 = 0, s2 = 0, s3 = 0, s4 = 0, s5 = 0, s6 = 0, s7 = 0;
  int i = lo;
  for (; i + 8 <= end; i += 8) {
    int e0 = csr[i], e1 = csr[i + 1], e2 = csr[i + 2], e3 = csr[i + 3];
    int e4 = csr[i + 4], e5 = csr[i + 5], e6 = csr[i + 6], e7 = csr[i + 7];
    s0 += __half2float(h[(size_t)e0 * 64 + lane]);
    s1 += __half2float(h[(size_t)e1 * 64 + lane]);
    s2 += __half2float(h[(size_t)e2 * 64 + lane]);
    s3 += __half2float(h[(size_t)e3 * 64 + lane]);
    s4 += __half2float(h[(size_t)e4 * 64 + lane]);
    s5 += __half2float(h[(size_t)e5 * 64 + lane]);
    s6 += __half2float(h[(size_t)e6 * 64 + lane]);
    s7 += __half2float(h[(size_t)e7 * 64 + lane]);
  }
  for (; i < end; ++i) s0 += __half2float(h[(size_t)csr[i] * 64 + lane]);
  float s = ((s0 + s1) + (s2 + s3)) + ((s4 + s5) + (s6 + s7));
  Xe[(size_t)w * 64 + lane] = __float2half(s * invE[w]);
}

// ---- E->V pull: z[v] = mean Xe[dst[...]]  (fp16 in/out) ----
__global__ void __launch_bounds__(256) zgather_k(const __half* __restrict__ Xe,
    const int* __restrict__ dstArr, const int* __restrict__ roff,
    __half* __restrict__ z, int n) {
  int lane = threadIdx.x & 63;
  int w = (blockIdx.x * blockDim.x + threadIdx.x) >> 6;
  if (w >= n) return;
  int lo = roff[w], hi = roff[w + 1];
  float s0 = 0, s1 = 0, s2 = 0, s3 = 0, s4 = 0, s5 = 0, s6 = 0, s7 = 0;
  int i = lo;
  for (; i + 8 <= hi; i += 8) {
    int e0 = dstArr[i], e1 = dstArr[i + 1], e2 = dstArr[i + 2], e3 = dstArr[i + 3];
    int e4 = dstArr[i + 4], e5 = dstArr[i + 5], e6 = dstArr[i + 6], e7 = dstArr[i + 7];
    s0 += __half2float(Xe[(size_t)e0 * 64 + lane]);
    s1 += __half2float(Xe[(size_t)e1 * 64 + lane]);
    s2 += __half2float(Xe[(size_t)e2 * 64 + lane]);
    s3 += __half2float(Xe[(size_t)e3 * 64 + lane]);
    s4 += __half2float(Xe[(size_t)e4 * 64 + lane]);
    s5 += __half2float(Xe[(size_t)e5 * 64 + lane]);
    s6 += __half2float(Xe[(size_t)e6 * 64 + lane]);
    s7 += __half2float(Xe[(size_t)e7 * 64 + lane]);
  }
  for (; i < hi; ++i) s0 += __half2float(Xe[(size_t)dstArr[i] * 64 + lane]);
  float s = ((s0 + s1) + (s2 + s3)) + ((s4 + s5) + (s6 + s7));
  z[(size_t)w * 64 + lane] = __float2half((hi > lo) ? s / (float)(hi - lo) : 0.0f);
}

// ---- fused: res = 0.5*x0 + 0.5*(cat(x,z)@W2+b2) [masked]; x = relu(res@W3+b3) ----
__global__ void __launch_bounds__(256) catmm_w3_k(float* x, const __half* __restrict__ z,
    const float* __restrict__ x0, const int* __restrict__ roff,
    const float* __restrict__ W2, const float* __restrict__ b2,
    const float* __restrict__ W3, const float* __restrict__ b3, int n) {
  int lane = threadIdx.x & 63;
  int wid = (blockIdx.x * blockDim.x + threadIdx.x) >> 6;
  int nw = (gridDim.x * blockDim.x) >> 6;
  float w2r[128], w3r[64];
#pragma unroll
  for (int k = 0; k < 128; ++k) w2r[k] = W2[k * 64 + lane];
#pragma unroll
  for (int k = 0; k < 64; ++k) w3r[k] = W3[k * 64 + lane];
  float bb2 = b2[lane], bb3 = b3[lane];
  for (int row = wid; row < n; row += nw) {
    float a   = x[(size_t)row * 64 + lane];
    float zz  = __half2float(z[(size_t)row * 64 + lane]);
    float x0v = x0[(size_t)row * 64 + lane];
    int deg = roff[row + 1] - roff[row];
    float acc = bb2;
#pragma unroll
    for (int k = 0; k < 64; ++k) acc = fmaf(rl(a, k), w2r[k], acc);
#pragma unroll
    for (int k = 0; k < 64; ++k) acc = fmaf(rl(zz, k), w2r[64 + k], acc);
    float res = 0.5f * x0v;
    res = (deg > 0) ? fmaf(0.5f, acc, res) : res;
    float o = bb3;
#pragma unroll
    for (int k = 0; k < 64; ++k) o = fmaf(rl(res, k), w3r[k], o);
    x[(size_t)row * 64 + lane] = fmaxf(o, 0.0f);
  }
}

// ---- classifier: out = relu(x@Wc1+bc1)@Wc2+bc2 ----
__global__ void __launch_bounds__(256) classifier_k(const float* __restrict__ x,
    const float* __restrict__ Wc1, const float* __restrict__ bc1,
    const float* __restrict__ Wc2, const float* __restrict__ bc2,
    float* __restrict__ out, int n) {
  int lane = threadIdx.x & 63;
  int j2 = lane & 31;
  int wid = (blockIdx.x * blockDim.x + threadIdx.x) >> 6;
  int nw = (gridDim.x * blockDim.x) >> 6;
  float w1[64], w2[64];
#pragma unroll
  for (int k = 0; k < 64; ++k) w1[k] = Wc1[k * 64 + lane];
#pragma unroll
  for (int k = 0; k < 64; ++k) w2[k] = Wc2[k * 32 + j2];
  float b1v = bc1[lane], b2v = bc2[j2];
  for (int row = wid; row < n; row += nw) {
    float a = x[(size_t)row * 64 + lane];
    float t = b1v;
#pragma unroll
    for (int k = 0; k < 64; ++k) t = fmaf(rl(a, k), w1[k], t);
    t = fmaxf(t, 0.0f);
    float o = b2v;
#pragma unroll
    for (int k = 0; k < 64; ++k) o = fmaf(rl(t, k), w2[k], o);
    if (lane < 32) out[(size_t)row * 32 + lane] = o;
  }
}

// ---- per-graph mean readout over sorted batch ids ----
__global__ void __launch_bounds__(256) readout_k(const float* __restrict__ xc,
    const int* __restrict__ batch, int n, float* __restrict__ out) {
  __shared__ float part[8][32];
  int g = blockIdx.x;
  int lo = lbound(batch, n, g);
  int hi = lbound(batch, n, g + 1);
  int j = threadIdx.x & 31, r = threadIdx.x >> 5;
  float acc = 0.0f;
  for (int i = lo + r; i < hi; i += 8) acc += xc[(size_t)i * 32 + j];
  part[r][j] = acc;
  __syncthreads();
  if (threadIdx.x < 32) {
    float s = 0.0f;
#pragma unroll
    for (int rr = 0; rr < 8; ++rr) s += part[rr][j];
    out[g * 32 + j] = (hi > lo) ? s / (float)(hi - lo) : 0.0f;
  }
}

extern "C" void kernel_launch(void* const* d_in, const int* in_sizes, int n_in,
                              void* d_out, int out_size, void* d_ws, size_t ws_size,
                              hipStream_t stream) {
  const float* X    = (const float*)d_in[0];
  const int*   src  = (const int*)d_in[1];
  const int*   dst  = (const int*)d_in[2];
  const int*   batch= (const int*)d_in[3];
  const float* W_in = (const float*)d_in[4];
  const float* b_in = (const float*)d_in[5];
  const float* W1a  = (const float*)d_in[6];
  const float* b1a  = (const float*)d_in[7];
  const float* W1b  = (const float*)d_in[8];
  const float* b1b  = (const float*)d_in[9];
  const float* W2   = (const float*)d_in[10];
  const float* b2   = (const float*)d_in[11];
  const float* W3   = (const float*)d_in[12];
  const float* b3   = (const float*)d_in[13];
  const float* Wc1  = (const float*)d_in[14];
  const float* bc1  = (const float*)d_in[15];
  const float* Wc2  = (const float*)d_in[16];
  const float* bc2  = (const float*)d_in[17];
  float* out = (float*)d_out;

  // workspace layout (~80 MB)
  float* p  = (float*)d_ws;
  float* x  = p; p += (size_t)NN * 64;   // 25.6 MB
  float* x0 = p; p += (size_t)NN * 64;   // 25.6 MB
  __half* hz = (__half*)p; p += (size_t)NN * 32;  // 12.8 MB: h, then z, then classifier out
  __half* Xe = (__half*)p; p += (size_t)NE * 32;  // 6.4 MB
  float* invE = p; p += NE;
  int* q     = (int*)p;
  int* cnt   = q; q += NE;
  int* off   = q; q += NE;
  int* cursor= q; q += NE;
  int* roff  = q; q += NN + 1;
  int* csr   = q; q += NZ;               // 5.12 MB
  int* bsum  = q; q += 256;
  __half* h = hz;
  __half* z = hz;              // alias: h fully consumed by ve_pull before zgather writes z
  float* outc = (float*)hz;    // alias: hz dead after last catmm_w3

  // CSR-by-dst + row offsets (once per call)
  hipMemsetAsync(cnt, 0, (size_t)NE * sizeof(int), stream);
  count_k<<<(NZ + 255) / 256, 256, 0, stream>>>(dst, cnt, NZ);
  bsum_k<<<NB, 256, 0, stream>>>(cnt, bsum, NE);
  bscan_k<<<1, 256, 0, stream>>>(bsum, NB);
  csroff_k<<<NB, 256, 0, stream>>>(cnt, bsum, off, cursor, invE, NE);
  fill_k<<<(NZ + 255) / 256, 256, 0, stream>>>(src, dst, cursor, csr, NZ);
  rowoff_diff_k<<<(NZ + 255) / 256, 256, 0, stream>>>(src, roff, NN, NZ);

  mm_in_k<<<1024, 256, 0, stream>>>(X, W_in, b_in, x, x0, NN);

  for (int l = 0; l < 2; ++l) {
    mm_dual_k<<<2048, 256, 0, stream>>>(x, W1a, b1a, W1b, b1b, h, NN);
    ve_pull_k<<<(NE + 3) / 4, 256, 0, stream>>>(h, csr, off, cnt, invE, Xe, NE);
    zgather_k<<<(NN + 3) / 4, 256, 0, stream>>>(Xe, dst, roff, z, NN);
    catmm_w3_k<<<2048, 256, 0, stream>>>(x, z, x0, roff, W2, b2, W3, b3, NN);
  }

  classifier_k<<<2048, 256, 0, stream>>>(x, Wc1, bc1, Wc2, bc2, outc, NN);
  readout_k<<<NG, 256, 0, stream>>>(outc, batch, NN, out);
}